// Round 13
// baseline (230.952 us; speedup 1.0000x reference)
//
#include <hip/hip_runtime.h>
#include <hip/hip_bf16.h>
#include <math.h>

#define NUSER 100000
#define NITEM 100000
#define NEDGE 600000
#define HID   128
#define OUTD  64
#define LDA   136   // padded LDS stride in bf16 elems (proj kernel)
#define LDF   132   // padded LDS stride in f32 elems (finalize Al)
#define PROJ_BLOCKS ((NUSER + NITEM) / 64)          // 3125
#define EPB   ((2 * NEDGE + PROJ_BLOCKS - 1) / PROJ_BLOCKS)   // 384 edges/block

typedef __attribute__((ext_vector_type(8))) short  bf16x8;
typedef __attribute__((ext_vector_type(4))) float  f32x4;
typedef __attribute__((ext_vector_type(4))) unsigned short u16x4;

__device__ inline unsigned short f2bf(float f) {
    __hip_bfloat16 h = __float2bfloat16(f);
    return *reinterpret_cast<unsigned short*>(&h);
}

__device__ inline void bf2x(unsigned int u, float& lo, float& hi) {
    union { unsigned int i; float f; } a, b;
    a.i = u << 16;
    b.i = u & 0xffff0000u;
    lo = a.f; hi = b.f;
}

// ---------------------------------------------------------------------------
// Stage 0 (fused): zero deg1|deg2  +  W_proj -> bf16 transposed wt[col][k]
// ---------------------------------------------------------------------------
__global__ void prep(const float* __restrict__ W, unsigned short* __restrict__ wt,
                     int* __restrict__ deg) {
    int i = blockIdx.x * 256 + threadIdx.x;
    if (i < 2 * NUSER) deg[i] = 0;
    if (i < 128 * 128) {
        int k = i >> 7, c = i & 127;
        wt[c * 128 + k] = f2bf(W[i]);
    }
}

// ---------------------------------------------------------------------------
// Stage 1: degree histograms; atomic return = rank. 1 edge/thread (max MLP —
// R6-measured; 2/thread serializes dependent atomic round-trips, R12 −5µs).
// ---------------------------------------------------------------------------
__global__ void count_rank(const int* __restrict__ e1d, const int* __restrict__ e2d,
                           int* __restrict__ deg1, int* __restrict__ deg2,
                           int* __restrict__ rank) {
    int i = blockIdx.x * blockDim.x + threadIdx.x;
    if (i < NEDGE)            rank[i] = atomicAdd(&deg1[e1d[i]], 1);
    else if (i < 2 * NEDGE)   rank[i] = atomicAdd(&deg2[e2d[i - NEDGE]], 1);
}

// ---------------------------------------------------------------------------
// Stage 2: exclusive scan of (deg1+deg2) -> off[0..NUSER]
// ---------------------------------------------------------------------------
#define SCAN_BLOCKS 391   // ceil(100000/256)

__global__ __launch_bounds__(256) void scanA(
    const int* __restrict__ deg1, const int* __restrict__ deg2,
    int* __restrict__ off, int* __restrict__ bsum)
{
    __shared__ int sh[256];
    int t = threadIdx.x;
    int i = blockIdx.x * 256 + t;
    int d = (i < NUSER) ? deg1[i] + deg2[i] : 0;
    sh[t] = d;
    __syncthreads();
    for (int dd = 1; dd < 256; dd <<= 1) {
        int v = (t >= dd) ? sh[t - dd] : 0;
        __syncthreads();
        sh[t] += v;
        __syncthreads();
    }
    if (i < NUSER) off[i] = (t > 0) ? sh[t - 1] : 0;
    if (t == 255) bsum[blockIdx.x] = sh[255];
}

__global__ __launch_bounds__(512) void scanB(int* __restrict__ bsum, int* __restrict__ off) {
    __shared__ int sh[512];
    int t = threadIdx.x;
    int v = (t < SCAN_BLOCKS) ? bsum[t] : 0;
    sh[t] = v;
    __syncthreads();
    for (int dd = 1; dd < 512; dd <<= 1) {
        int x = (t >= dd) ? sh[t - dd] : 0;
        __syncthreads();
        sh[t] += x;
        __syncthreads();
    }
    if (t < SCAN_BLOCKS) bsum[t] = (t > 0) ? sh[t - 1] : 0;
    if (t == 511) off[NUSER] = sh[511];
}

__global__ __launch_bounds__(256) void scanC(int* __restrict__ off, const int* __restrict__ bsum) {
    int i = blockIdx.x * 256 + threadIdx.x;
    if (i < NUSER) off[i] += bsum[blockIdx.x];
}

// ---------------------------------------------------------------------------
// Stage 3 (fused): bf16-MFMA projection (64 rows/block, no Wl in LDS,
// preloaded B-fragments) + adjacency-fill tail. [R8/R12-measured ~76µs]
// ---------------------------------------------------------------------------
__global__ __launch_bounds__(256) void proj_fill(
    const float* __restrict__ xu, const float* __restrict__ xi,
    const unsigned short* __restrict__ wt, const float* __restrict__ b,
    unsigned short* __restrict__ h,
    const int* __restrict__ e1s, const int* __restrict__ e1d,
    const int* __restrict__ e2s, const int* __restrict__ e2d,
    const int* __restrict__ off, const int* __restrict__ deg1,
    const int* __restrict__ rank, int* __restrict__ adj)
{
    __shared__ unsigned short Al[64 * LDA];   // 17.4 KB
    const int tid = threadIdx.x;
    const int r0  = blockIdx.x * 64;

    float4 v[8];
    #pragma unroll
    for (int j = 0; j < 8; j++) {
        int i = tid + j * 256;            // 0..2047
        int row = i >> 5, c4 = i & 31;
        int gr = r0 + row;
        const float4* src = (gr < NUSER)
            ? (const float4*)(xu + (size_t)gr * 128)
            : (const float4*)(xi + (size_t)(gr - NUSER) * 128);
        v[j] = src[c4];
    }
    __builtin_amdgcn_sched_barrier(0);
    #pragma unroll
    for (int j = 0; j < 8; j++) {
        int i = tid + j * 256;
        int row = i >> 5, c4 = i & 31;
        u16x4 p;
        p.x = f2bf(v[j].x); p.y = f2bf(v[j].y); p.z = f2bf(v[j].z); p.w = f2bf(v[j].w);
        *(u16x4*)&Al[row * LDA + c4 * 4] = p;
    }
    __syncthreads();

    const int w    = tid >> 6;
    const int lane = tid & 63;
    const int lrow = lane & 15;
    const int lk   = (lane >> 4) * 8;

    bf16x8 bfrag[4][2];
    #pragma unroll
    for (int kc = 0; kc < 4; kc++) {
        const int ko = kc * 32 + lk;
        bfrag[kc][0] = *(const bf16x8*)&wt[(size_t)(w * 32 + lrow) * 128 + ko];
        bfrag[kc][1] = *(const bf16x8*)&wt[(size_t)(w * 32 + 16 + lrow) * 128 + ko];
    }

    f32x4 acc[4][2] = {};
    #pragma unroll
    for (int kc = 0; kc < 4; kc++) {
        const int ko = kc * 32 + lk;
        #pragma unroll
        for (int rt = 0; rt < 4; rt++) {
            bf16x8 aa = *(const bf16x8*)&Al[(rt * 16 + lrow) * LDA + ko];
            acc[rt][0] = __builtin_amdgcn_mfma_f32_16x16x32_bf16(aa, bfrag[kc][0], acc[rt][0], 0, 0, 0);
            acc[rt][1] = __builtin_amdgcn_mfma_f32_16x16x32_bf16(aa, bfrag[kc][1], acc[rt][1], 0, 0, 0);
        }
    }

    __syncthreads();   // all Al reads done
    const float bv0 = b[w * 32 + lrow];
    const float bv1 = b[w * 32 + 16 + lrow];
    #pragma unroll
    for (int rt = 0; rt < 4; rt++) {
        #pragma unroll
        for (int ct = 0; ct < 2; ct++) {
            int col = w * 32 + ct * 16 + lrow;
            float bv = ct ? bv1 : bv0;
            #pragma unroll
            for (int r = 0; r < 4; r++) {
                int row = rt * 16 + (lane >> 4) * 4 + r;
                Al[row * LDA + col] = f2bf(acc[rt][ct][r] + bv);
            }
        }
    }
    __syncthreads();

    for (int i = tid; i < 1024; i += 256) {
        int row = i >> 4, c8 = i & 15;
        *(bf16x8*)&h[(size_t)(r0 + row) * 128 + c8 * 8] =
            *(const bf16x8*)&Al[row * LDA + c8 * 8];
    }

    // ---- adjacency-fill tail: this block's 384-edge chunk (no atomics) ----
    const int base = blockIdx.x * EPB;
    const int lim  = (base + EPB < 2 * NEDGE) ? base + EPB : 2 * NEDGE;
    for (int i = base + tid; i < lim; i += 256) {
        int src, dst, slot;
        if (i < NEDGE) {
            src  = e1s[i];
            dst  = e1d[i];
            slot = off[dst] + rank[i];
        } else {
            int j = i - NEDGE;
            src  = NUSER + e2s[j];
            dst  = e2d[j];
            slot = off[dst] + deg1[dst] + rank[i];
        }
        adj[slot] = src;
    }
}

// ---------------------------------------------------------------------------
// Stage 4: gather — one wave per dst node; 4-deep edge batches [R6/R12 loop];
// output packed bf16 (halves stream-out; absmax validated in R7/R8).
// ---------------------------------------------------------------------------
__global__ __launch_bounds__(256) void gather(
    const unsigned short* __restrict__ h, const int* __restrict__ adj,
    const int* __restrict__ off, const int* __restrict__ deg1,
    const int* __restrict__ deg2,
    const float* __restrict__ al1p, const float* __restrict__ ar1p,
    const float* __restrict__ al2p, const float* __restrict__ ar2p,
    unsigned int* __restrict__ accb)
{
    int wid  = (int)((blockIdx.x * 256 + threadIdx.x) >> 6);
    int lane = threadIdx.x & 63;
    if (wid >= NUSER) return;

    const unsigned int* h32 = (const unsigned int*)h;

    const float al1 = al1p[0], al2 = al2p[0];
    const float sc  = ar1p[0] * (float)deg1[wid] + ar2p[0] * (float)deg2[wid];

    float lo, hi;
    bf2x(h32[(size_t)wid * 64 + lane], lo, hi);
    float sx = sc * lo, sy = sc * hi;

    int e    = off[wid];
    int eend = off[wid + 1];
    for (; e + 4 <= eend; e += 4) {
        int s0 = adj[e], s1 = adj[e + 1], s2 = adj[e + 2], s3 = adj[e + 3];
        unsigned int u0 = h32[(size_t)s0 * 64 + lane];
        unsigned int u1 = h32[(size_t)s1 * 64 + lane];
        unsigned int u2 = h32[(size_t)s2 * 64 + lane];
        unsigned int u3 = h32[(size_t)s3 * 64 + lane];
        float a0 = (s0 < NUSER) ? al1 : al2;
        float a1 = (s1 < NUSER) ? al1 : al2;
        float a2 = (s2 < NUSER) ? al1 : al2;
        float a3 = (s3 < NUSER) ? al1 : al2;
        float x0, y0, x1, y1, x2, y2, x3, y3;
        bf2x(u0, x0, y0); bf2x(u1, x1, y1); bf2x(u2, x2, y2); bf2x(u3, x3, y3);
        sx = fmaf(a0, x0, sx); sy = fmaf(a0, y0, sy);
        sx = fmaf(a1, x1, sx); sy = fmaf(a1, y1, sy);
        sx = fmaf(a2, x2, sx); sy = fmaf(a2, y2, sy);
        sx = fmaf(a3, x3, sx); sy = fmaf(a3, y3, sy);
    }
    for (; e < eend; e++) {
        int s0 = adj[e];
        float a0 = (s0 < NUSER) ? al1 : al2;
        float x0, y0;
        bf2x(h32[(size_t)s0 * 64 + lane], x0, y0);
        sx = fmaf(a0, x0, sx); sy = fmaf(a0, y0, sy);
    }

    sx = sx > 0.f ? sx : expm1f(sx);
    sy = sy > 0.f ? sy : expm1f(sy);
    accb[(size_t)wid * 64 + lane] = ((unsigned int)f2bf(sy) << 16) | (unsigned int)f2bf(sx);
}

// ---------------------------------------------------------------------------
// Stage 5: out_user = acc @ W_out + b_out (bf16 acc in, fp32 GEMM);
// also zeroes this block's out_item slice (elu(0) = 0).
// ---------------------------------------------------------------------------
__global__ __launch_bounds__(256) void finalize(
    const unsigned int* __restrict__ accb, const float* __restrict__ Wo,
    const float* __restrict__ bo, float* __restrict__ out,
    float* __restrict__ oitem)
{
    __shared__ float Wl[128 * 64];    // 32 KB
    __shared__ float Al[64 * LDF];    // 33.8 KB
    const int tid = threadIdx.x;
    const int n0  = blockIdx.x * 64;

    for (int i = tid; i < 128 * 64 / 4; i += 256)
        ((float4*)Wl)[i] = ((const float4*)Wo)[i];

    for (int i = tid; i < 4096; i += 256) {   // 64 rows x 64 dwords
        int row = i >> 6, d = i & 63;
        int gr = n0 + row;
        float lo = 0.f, hi = 0.f;
        if (gr < NUSER) bf2x(accb[(size_t)gr * 64 + d], lo, hi);
        *(float2*)&Al[row * LDF + d * 2] = make_float2(lo, hi);
    }
    __syncthreads();

    // zero out_item slice (independent of the GEMM)
    for (int i = tid; i < 2048; i += 256) {
        int row = i >> 5, c4 = i & 31;
        int gr = n0 + row;
        if (gr < NUSER)
            ((float4*)(oitem + (size_t)gr * 128))[c4] = make_float4(0.f, 0.f, 0.f, 0.f);
    }

    const int tr = tid >> 4;
    const int tc = tid & 15;

    float s[4][4];
    {
        float4 bv = *(const float4*)&bo[tc * 4];
        #pragma unroll
        for (int i = 0; i < 4; i++) {
            s[i][0] = bv.x; s[i][1] = bv.y; s[i][2] = bv.z; s[i][3] = bv.w;
        }
    }

    for (int k0 = 0; k0 < 128; k0 += 4) {
        float4 av[4];
        #pragma unroll
        for (int i = 0; i < 4; i++)
            av[i] = *(const float4*)&Al[(tr * 4 + i) * LDF + k0];
        #pragma unroll
        for (int kk = 0; kk < 4; kk++) {
            float4 wv = *(const float4*)&Wl[(k0 + kk) * 64 + tc * 4];
            #pragma unroll
            for (int i = 0; i < 4; i++) {
                float a = (&av[i].x)[kk];
                s[i][0] = fmaf(a, wv.x, s[i][0]);
                s[i][1] = fmaf(a, wv.y, s[i][1]);
                s[i][2] = fmaf(a, wv.z, s[i][2]);
                s[i][3] = fmaf(a, wv.w, s[i][3]);
            }
        }
    }

    #pragma unroll
    for (int i = 0; i < 4; i++) {
        int gr = n0 + tr * 4 + i;
        if (gr < NUSER) {
            float4 o = make_float4(s[i][0], s[i][1], s[i][2], s[i][3]);
            *(float4*)&out[(size_t)gr * 64 + tc * 4] = o;
        }
    }
}

extern "C" void kernel_launch(void* const* d_in, const int* in_sizes, int n_in,
                              void* d_out, int out_size, void* d_ws, size_t ws_size,
                              hipStream_t stream) {
    const float* xu  = (const float*)d_in[0];
    const float* xi  = (const float*)d_in[1];
    const float* Wp  = (const float*)d_in[2];
    const float* bp  = (const float*)d_in[3];
    const float* Wo  = (const float*)d_in[4];
    const float* bo  = (const float*)d_in[5];
    const float* al1 = (const float*)d_in[6];
    const float* ar1 = (const float*)d_in[7];
    const float* al2 = (const float*)d_in[8];
    const float* ar2 = (const float*)d_in[9];
    const int* e1s = (const int*)d_in[10];
    const int* e1d = (const int*)d_in[11];
    const int* e2s = (const int*)d_in[12];
    const int* e2d = (const int*)d_in[13];

    float* out   = (float*)d_out;
    float* oitem = out + (size_t)NUSER * OUTD;   // out_item region (pure output)

    // Workspace: h bf16 (51.2MB) | wt bf16 (32KB) | accb bf16 (25.6MB)
    unsigned short* h    = (unsigned short*)d_ws;
    unsigned short* wt   = h + (size_t)(NUSER + NITEM) * HID;
    unsigned int*   accb = (unsigned int*)(wt + 128 * 128);

    // Int metadata in the out_user region (free until finalize):
    // deg1[NU] | deg2[NU] | off[NU+1] | bsum[512] | adj[2E] | rank[2E]
    int* meta = (int*)out;
    int* deg1 = meta;
    int* deg2 = meta + NUSER;
    int* off  = meta + 2 * NUSER;
    int* bsum = meta + 3 * NUSER + 64;
    int* adj  = meta + 3 * NUSER + 1024;
    int* rank = adj + 2 * NEDGE;             // total ~10.6 MB < 25.6 MB

    // 0: zero degs + W -> bf16 transposed
    prep<<<(2 * NUSER + 255) / 256, 256, 0, stream>>>(Wp, wt, deg1);

    // 1: degree histograms + per-edge rank (1 edge/thread, max atomic MLP)
    count_rank<<<(2 * NEDGE + 255) / 256, 256, 0, stream>>>(e1d, e2d, deg1, deg2, rank);

    // 2: exclusive scan -> off
    scanA<<<SCAN_BLOCKS, 256, 0, stream>>>(deg1, deg2, off, bsum);
    scanB<<<1, 512, 0, stream>>>(bsum, off);
    scanC<<<SCAN_BLOCKS, 256, 0, stream>>>(off, bsum);

    // 3: MFMA projection + adjacency fill (fused)
    proj_fill<<<PROJ_BLOCKS, 256, 0, stream>>>(xu, xi, wt, bp, h,
                                               e1s, e1d, e2s, e2d,
                                               off, deg1, rank, adj);

    // 4: atomic-free gather + ELU (bf16 packed out)
    gather<<<(NUSER * 64) / 256, 256, 0, stream>>>(h, adj, off, deg1, deg2,
                                                   al1, ar1, al2, ar2, accb);

    // 5: out_user GEMM + zero out_item
    finalize<<<(NUSER + 63) / 64, 256, 0, stream>>>(accb, Wo, bo, out, oitem);
}

// Round 14
// 216.458 us; speedup vs baseline: 1.0670x; 1.0670x over previous
//
#include <hip/hip_runtime.h>
#include <hip/hip_bf16.h>
#include <math.h>

#define NUSER 100000
#define NITEM 100000
#define NEDGE 600000
#define HID   128
#define OUTD  64
#define LDA   136   // padded LDS stride in bf16 elems (proj kernel)
#define LDF   132   // padded LDS stride in f32 elems (finalize Al)
#define PROJ_BLOCKS ((NUSER + NITEM) / 64)          // 3125
#define EPB   ((2 * NEDGE + PROJ_BLOCKS - 1) / PROJ_BLOCKS)   // 384 edges/block

typedef __attribute__((ext_vector_type(8))) short  bf16x8;
typedef __attribute__((ext_vector_type(4))) float  f32x4;
typedef __attribute__((ext_vector_type(4))) unsigned short u16x4;

__device__ inline unsigned short f2bf(float f) {
    __hip_bfloat16 h = __float2bfloat16(f);
    return *reinterpret_cast<unsigned short*>(&h);
}

__device__ inline void bf2x(unsigned int u, float& lo, float& hi) {
    union { unsigned int i; float f; } a, b;
    a.i = u << 16;
    b.i = u & 0xffff0000u;
    lo = a.f; hi = b.f;
}

// ---------------------------------------------------------------------------
// Stage 0 (fused): zero deg1|deg2  +  W_proj -> bf16 transposed wt[col][k]
// ---------------------------------------------------------------------------
__global__ void prep(const float* __restrict__ W, unsigned short* __restrict__ wt,
                     int* __restrict__ deg) {
    int i = blockIdx.x * 256 + threadIdx.x;
    if (i < 2 * NUSER) deg[i] = 0;
    if (i < 128 * 128) {
        int k = i >> 7, c = i & 127;
        wt[c * 128 + k] = f2bf(W[i]);
    }
}

// ---------------------------------------------------------------------------
// Stage 1: degree histograms; atomic return = rank. 1 edge/thread — max
// atomic MLP (R6-measured; 2/thread serializes round-trips, +19µs R12).
// ---------------------------------------------------------------------------
__global__ void count_rank(const int* __restrict__ e1d, const int* __restrict__ e2d,
                           int* __restrict__ deg1, int* __restrict__ deg2,
                           int* __restrict__ rank) {
    int i = blockIdx.x * blockDim.x + threadIdx.x;
    if (i < NEDGE)            rank[i] = atomicAdd(&deg1[e1d[i]], 1);
    else if (i < 2 * NEDGE)   rank[i] = atomicAdd(&deg2[e2d[i - NEDGE]], 1);
}

// ---------------------------------------------------------------------------
// Stage 2: exclusive scan of (deg1+deg2) -> off[0..NUSER]
// ---------------------------------------------------------------------------
#define SCAN_BLOCKS 391   // ceil(100000/256)

__global__ __launch_bounds__(256) void scanA(
    const int* __restrict__ deg1, const int* __restrict__ deg2,
    int* __restrict__ off, int* __restrict__ bsum)
{
    __shared__ int sh[256];
    int t = threadIdx.x;
    int i = blockIdx.x * 256 + t;
    int d = (i < NUSER) ? deg1[i] + deg2[i] : 0;
    sh[t] = d;
    __syncthreads();
    for (int dd = 1; dd < 256; dd <<= 1) {
        int v = (t >= dd) ? sh[t - dd] : 0;
        __syncthreads();
        sh[t] += v;
        __syncthreads();
    }
    if (i < NUSER) off[i] = (t > 0) ? sh[t - 1] : 0;
    if (t == 255) bsum[blockIdx.x] = sh[255];
}

__global__ __launch_bounds__(512) void scanB(int* __restrict__ bsum, int* __restrict__ off) {
    __shared__ int sh[512];
    int t = threadIdx.x;
    int v = (t < SCAN_BLOCKS) ? bsum[t] : 0;
    sh[t] = v;
    __syncthreads();
    for (int dd = 1; dd < 512; dd <<= 1) {
        int x = (t >= dd) ? sh[t - dd] : 0;
        __syncthreads();
        sh[t] += x;
        __syncthreads();
    }
    if (t < SCAN_BLOCKS) bsum[t] = (t > 0) ? sh[t - 1] : 0;
    if (t == 511) off[NUSER] = sh[511];
}

__global__ __launch_bounds__(256) void scanC(int* __restrict__ off, const int* __restrict__ bsum) {
    int i = blockIdx.x * 256 + threadIdx.x;
    if (i < NUSER) off[i] += bsum[blockIdx.x];
}

// ---------------------------------------------------------------------------
// Stage 3 (fused): bf16-MFMA projection (64 rows/block, no Wl in LDS,
// preloaded B-fragments, 8-deep staging) + adjacency-fill tail.
// [R8/R12/R13-measured ~75-77µs]
// ---------------------------------------------------------------------------
__global__ __launch_bounds__(256) void proj_fill(
    const float* __restrict__ xu, const float* __restrict__ xi,
    const unsigned short* __restrict__ wt, const float* __restrict__ b,
    unsigned short* __restrict__ h,
    const int* __restrict__ e1s, const int* __restrict__ e1d,
    const int* __restrict__ e2s, const int* __restrict__ e2d,
    const int* __restrict__ off, const int* __restrict__ deg1,
    const int* __restrict__ rank, int* __restrict__ adj)
{
    __shared__ unsigned short Al[64 * LDA];   // 17.4 KB
    const int tid = threadIdx.x;
    const int r0  = blockIdx.x * 64;

    float4 v[8];
    #pragma unroll
    for (int j = 0; j < 8; j++) {
        int i = tid + j * 256;            // 0..2047
        int row = i >> 5, c4 = i & 31;
        int gr = r0 + row;
        const float4* src = (gr < NUSER)
            ? (const float4*)(xu + (size_t)gr * 128)
            : (const float4*)(xi + (size_t)(gr - NUSER) * 128);
        v[j] = src[c4];
    }
    __builtin_amdgcn_sched_barrier(0);
    #pragma unroll
    for (int j = 0; j < 8; j++) {
        int i = tid + j * 256;
        int row = i >> 5, c4 = i & 31;
        u16x4 p;
        p.x = f2bf(v[j].x); p.y = f2bf(v[j].y); p.z = f2bf(v[j].z); p.w = f2bf(v[j].w);
        *(u16x4*)&Al[row * LDA + c4 * 4] = p;
    }
    __syncthreads();

    const int w    = tid >> 6;
    const int lane = tid & 63;
    const int lrow = lane & 15;
    const int lk   = (lane >> 4) * 8;

    bf16x8 bfrag[4][2];
    #pragma unroll
    for (int kc = 0; kc < 4; kc++) {
        const int ko = kc * 32 + lk;
        bfrag[kc][0] = *(const bf16x8*)&wt[(size_t)(w * 32 + lrow) * 128 + ko];
        bfrag[kc][1] = *(const bf16x8*)&wt[(size_t)(w * 32 + 16 + lrow) * 128 + ko];
    }

    f32x4 acc[4][2] = {};
    #pragma unroll
    for (int kc = 0; kc < 4; kc++) {
        const int ko = kc * 32 + lk;
        #pragma unroll
        for (int rt = 0; rt < 4; rt++) {
            bf16x8 aa = *(const bf16x8*)&Al[(rt * 16 + lrow) * LDA + ko];
            acc[rt][0] = __builtin_amdgcn_mfma_f32_16x16x32_bf16(aa, bfrag[kc][0], acc[rt][0], 0, 0, 0);
            acc[rt][1] = __builtin_amdgcn_mfma_f32_16x16x32_bf16(aa, bfrag[kc][1], acc[rt][1], 0, 0, 0);
        }
    }

    __syncthreads();   // all Al reads done
    const float bv0 = b[w * 32 + lrow];
    const float bv1 = b[w * 32 + 16 + lrow];
    #pragma unroll
    for (int rt = 0; rt < 4; rt++) {
        #pragma unroll
        for (int ct = 0; ct < 2; ct++) {
            int col = w * 32 + ct * 16 + lrow;
            float bv = ct ? bv1 : bv0;
            #pragma unroll
            for (int r = 0; r < 4; r++) {
                int row = rt * 16 + (lane >> 4) * 4 + r;
                Al[row * LDA + col] = f2bf(acc[rt][ct][r] + bv);
            }
        }
    }
    __syncthreads();

    for (int i = tid; i < 1024; i += 256) {
        int row = i >> 4, c8 = i & 15;
        *(bf16x8*)&h[(size_t)(r0 + row) * 128 + c8 * 8] =
            *(const bf16x8*)&Al[row * LDA + c8 * 8];
    }

    // ---- adjacency-fill tail: this block's 384-edge chunk (no atomics) ----
    const int base = blockIdx.x * EPB;
    const int lim  = (base + EPB < 2 * NEDGE) ? base + EPB : 2 * NEDGE;
    for (int i = base + tid; i < lim; i += 256) {
        int src, dst, slot;
        if (i < NEDGE) {
            src  = e1s[i];
            dst  = e1d[i];
            slot = off[dst] + rank[i];
        } else {
            int j = i - NEDGE;
            src  = NUSER + e2s[j];
            dst  = e2d[j];
            slot = off[dst] + deg1[dst] + rank[i];
        }
        adj[slot] = src;
    }
}

// ---------------------------------------------------------------------------
// Stage 4: gather — one wave per dst node; 4-deep edge batches; fp32 acc
// written to the out_item region. [R6's tail — best-measured config]
// ---------------------------------------------------------------------------
__global__ __launch_bounds__(256) void gather(
    const unsigned short* __restrict__ h, const int* __restrict__ adj,
    const int* __restrict__ off, const int* __restrict__ deg1,
    const int* __restrict__ deg2,
    const float* __restrict__ al1p, const float* __restrict__ ar1p,
    const float* __restrict__ al2p, const float* __restrict__ ar2p,
    float* __restrict__ acc)
{
    int wid  = (int)((blockIdx.x * 256 + threadIdx.x) >> 6);
    int lane = threadIdx.x & 63;
    if (wid >= NUSER) return;

    const unsigned int* h32 = (const unsigned int*)h;

    const float al1 = al1p[0], al2 = al2p[0];
    const float sc  = ar1p[0] * (float)deg1[wid] + ar2p[0] * (float)deg2[wid];

    float lo, hi;
    bf2x(h32[(size_t)wid * 64 + lane], lo, hi);
    float sx = sc * lo, sy = sc * hi;

    int e    = off[wid];
    int eend = off[wid + 1];
    for (; e + 4 <= eend; e += 4) {
        int s0 = adj[e], s1 = adj[e + 1], s2 = adj[e + 2], s3 = adj[e + 3];
        unsigned int u0 = h32[(size_t)s0 * 64 + lane];
        unsigned int u1 = h32[(size_t)s1 * 64 + lane];
        unsigned int u2 = h32[(size_t)s2 * 64 + lane];
        unsigned int u3 = h32[(size_t)s3 * 64 + lane];
        float a0 = (s0 < NUSER) ? al1 : al2;
        float a1 = (s1 < NUSER) ? al1 : al2;
        float a2 = (s2 < NUSER) ? al1 : al2;
        float a3 = (s3 < NUSER) ? al1 : al2;
        float x0, y0, x1, y1, x2, y2, x3, y3;
        bf2x(u0, x0, y0); bf2x(u1, x1, y1); bf2x(u2, x2, y2); bf2x(u3, x3, y3);
        sx = fmaf(a0, x0, sx); sy = fmaf(a0, y0, sy);
        sx = fmaf(a1, x1, sx); sy = fmaf(a1, y1, sy);
        sx = fmaf(a2, x2, sx); sy = fmaf(a2, y2, sy);
        sx = fmaf(a3, x3, sx); sy = fmaf(a3, y3, sy);
    }
    for (; e < eend; e++) {
        int s0 = adj[e];
        float a0 = (s0 < NUSER) ? al1 : al2;
        float x0, y0;
        bf2x(h32[(size_t)s0 * 64 + lane], x0, y0);
        sx = fmaf(a0, x0, sx); sy = fmaf(a0, y0, sy);
    }

    sx = sx > 0.f ? sx : expm1f(sx);
    sy = sy > 0.f ? sy : expm1f(sy);
    ((float2*)(acc + (size_t)wid * 128))[lane] = make_float2(sx, sy);
}

// ---------------------------------------------------------------------------
// Stage 5: out_user = acc @ W_out + b_out; then zero this block's acc slice
// (acc region == out_item, which must be elu(0) = 0). [R6's finalize]
// ---------------------------------------------------------------------------
__global__ __launch_bounds__(256) void finalize(
    const float* __restrict__ acc, const float* __restrict__ Wo,
    const float* __restrict__ bo, float* __restrict__ out,
    float* __restrict__ accw)
{
    __shared__ float Wl[128 * 64];    // 32 KB
    __shared__ float Al[64 * LDF];    // 33.8 KB
    const int tid = threadIdx.x;
    const int n0  = blockIdx.x * 64;

    for (int i = tid; i < 128 * 64 / 4; i += 256)
        ((float4*)Wl)[i] = ((const float4*)Wo)[i];

    for (int i = tid; i < 2048; i += 256) {
        int row = i >> 5, c4 = i & 31;
        int gr = n0 + row;
        float4 v = (gr < NUSER) ? ((const float4*)(acc + (size_t)gr * 128))[c4]
                                : make_float4(0.f, 0.f, 0.f, 0.f);
        *(float4*)&Al[row * LDF + c4 * 4] = v;
    }
    __syncthreads();

    // zero out_item slice now that it's staged in LDS
    for (int i = tid; i < 2048; i += 256) {
        int row = i >> 5, c4 = i & 31;
        int gr = n0 + row;
        if (gr < NUSER)
            ((float4*)(accw + (size_t)gr * 128))[c4] = make_float4(0.f, 0.f, 0.f, 0.f);
    }

    const int tr = tid >> 4;
    const int tc = tid & 15;

    float s[4][4];
    {
        float4 bv = *(const float4*)&bo[tc * 4];
        #pragma unroll
        for (int i = 0; i < 4; i++) {
            s[i][0] = bv.x; s[i][1] = bv.y; s[i][2] = bv.z; s[i][3] = bv.w;
        }
    }

    for (int k0 = 0; k0 < 128; k0 += 4) {
        float4 av[4];
        #pragma unroll
        for (int i = 0; i < 4; i++)
            av[i] = *(const float4*)&Al[(tr * 4 + i) * LDF + k0];
        #pragma unroll
        for (int kk = 0; kk < 4; kk++) {
            float4 wv = *(const float4*)&Wl[(k0 + kk) * 64 + tc * 4];
            #pragma unroll
            for (int i = 0; i < 4; i++) {
                float a = (&av[i].x)[kk];
                s[i][0] = fmaf(a, wv.x, s[i][0]);
                s[i][1] = fmaf(a, wv.y, s[i][1]);
                s[i][2] = fmaf(a, wv.z, s[i][2]);
                s[i][3] = fmaf(a, wv.w, s[i][3]);
            }
        }
    }

    #pragma unroll
    for (int i = 0; i < 4; i++) {
        int gr = n0 + tr * 4 + i;
        if (gr < NUSER) {
            float4 o = make_float4(s[i][0], s[i][1], s[i][2], s[i][3]);
            *(float4*)&out[(size_t)gr * 64 + tc * 4] = o;
        }
    }
}

extern "C" void kernel_launch(void* const* d_in, const int* in_sizes, int n_in,
                              void* d_out, int out_size, void* d_ws, size_t ws_size,
                              hipStream_t stream) {
    const float* xu  = (const float*)d_in[0];
    const float* xi  = (const float*)d_in[1];
    const float* Wp  = (const float*)d_in[2];
    const float* bp  = (const float*)d_in[3];
    const float* Wo  = (const float*)d_in[4];
    const float* bo  = (const float*)d_in[5];
    const float* al1 = (const float*)d_in[6];
    const float* ar1 = (const float*)d_in[7];
    const float* al2 = (const float*)d_in[8];
    const float* ar2 = (const float*)d_in[9];
    const int* e1s = (const int*)d_in[10];
    const int* e1d = (const int*)d_in[11];
    const int* e2s = (const int*)d_in[12];
    const int* e2d = (const int*)d_in[13];

    float* out = (float*)d_out;
    float* acc = out + (size_t)NUSER * OUTD;   // out_item region = fp32 elu buffer

    // Workspace: h bf16 (51.2MB) | wt bf16 (32KB)
    unsigned short* h  = (unsigned short*)d_ws;
    unsigned short* wt = h + (size_t)(NUSER + NITEM) * HID;

    // Int metadata in the out_user region (free until finalize):
    // deg1[NU] | deg2[NU] | off[NU+1] | bsum[512] | adj[2E] | rank[2E]
    int* meta = (int*)out;
    int* deg1 = meta;
    int* deg2 = meta + NUSER;
    int* off  = meta + 2 * NUSER;
    int* bsum = meta + 3 * NUSER + 64;
    int* adj  = meta + 3 * NUSER + 1024;
    int* rank = adj + 2 * NEDGE;             // total ~10.6 MB < 25.6 MB

    // 0: zero degs + W -> bf16 transposed
    prep<<<(2 * NUSER + 255) / 256, 256, 0, stream>>>(Wp, wt, deg1);

    // 1: degree histograms + per-edge rank (1 edge/thread, max atomic MLP)
    count_rank<<<(2 * NEDGE + 255) / 256, 256, 0, stream>>>(e1d, e2d, deg1, deg2, rank);

    // 2: exclusive scan -> off
    scanA<<<SCAN_BLOCKS, 256, 0, stream>>>(deg1, deg2, off, bsum);
    scanB<<<1, 512, 0, stream>>>(bsum, off);
    scanC<<<SCAN_BLOCKS, 256, 0, stream>>>(off, bsum);

    // 3: MFMA projection + adjacency fill (fused)
    proj_fill<<<PROJ_BLOCKS, 256, 0, stream>>>(xu, xi, wt, bp, h,
                                               e1s, e1d, e2s, e2d,
                                               off, deg1, rank, adj);

    // 4: atomic-free gather + ELU (fp32 acc in out_item region)
    gather<<<(NUSER * 64) / 256, 256, 0, stream>>>(h, adj, off, deg1, deg2,
                                                   al1, ar1, al2, ar2, acc);

    // 5: out_user GEMM + zero out_item
    finalize<<<(NUSER + 63) / 64, 256, 0, stream>>>(acc, Wo, bo, out, acc);
}